// Round 1
// baseline (14335.298 us; speedup 1.0000x reference)
//
#include <hip/hip_runtime.h>
#include <hip/hip_bf16.h>

namespace {

constexpr int Tn   = 512;   // timesteps
constexpr int In   = 256;   // input dim
constexpr int Hn   = 256;   // hidden dim
constexpr int Kn   = 512;   // I + H
constexpr int BBn  = 4;     // batch rows per workgroup
constexpr int NWn  = 64;    // workgroups (256 / BBn)
constexpr int NTHR = 512;   // 8 waves per workgroup
constexpr int APAD = 8;     // LDS row pad (bf16 elems) to break bank conflicts

typedef __attribute__((ext_vector_type(8))) short bf16x8;
typedef __attribute__((ext_vector_type(4))) float f32x4;

// Pack W [1024][512] f32 -> Wp bf16 in exact MFMA-B-fragment order:
// Wp[nt][kb][lane][e], nt=N-tile(16 cols), kb=K-block(32), lane 0..63, e 0..7.
// B[k][n] = W[n][k]; lane holds col n = nt*16 + (lane&15), k = kb*32 + (lane>>4)*8 + e.
__global__ void pack_w(const float* __restrict__ W, __hip_bfloat16* __restrict__ Wp) {
    int idx = blockIdx.x * 256 + threadIdx.x;      // 0 .. 524287
    int e   = idx & 7;
    int l   = (idx >> 3) & 63;
    int kb  = (idx >> 9) & 15;
    int nt  = idx >> 13;                           // 0..63
    int n   = nt * 16 + (l & 15);
    int k   = kb * 32 + (l >> 4) * 8 + e;
    Wp[idx] = __float2bfloat16(W[n * Kn + k]);
}

__device__ __forceinline__ float sigmoidf_(float x) { return 1.f / (1.f + __expf(-x)); }
__device__ __forceinline__ float tanhf_(float x)    { return 2.f / (1.f + __expf(-2.f * x)) - 1.f; }

// Persistent LSTM: each workgroup owns 4 batch rows for all 512 steps.
// A-operand tile [16][512] bf16 in LDS: rows 0..3 = [x_t | h_t], rows 4..15 zero pad.
// 8 waves; wave w owns hidden units [w*32, w*32+32): per gate g, N-tiles g*16 + w*2 + {0,1}.
__global__ __launch_bounds__(NTHR, 2) void lstm_fused(
    const float* __restrict__ X, const float* __restrict__ bias,
    const __hip_bfloat16* __restrict__ Wp, float* __restrict__ out)
{
    __shared__ __hip_bfloat16 A[16][Kn + APAD];

    const int tid  = threadIdx.x;
    const int wv   = tid >> 6;     // wave 0..7
    const int lane = tid & 63;
    const int l15  = lane & 15;
    const int lk   = lane >> 4;    // k-chunk 0..3
    const int b0   = blockIdx.x * BBn;

    // zero whole A tile once (pad rows stay zero forever; x/h rows rewritten per step)
    for (int i = tid; i < 16 * (Kn + APAD); i += NTHR)
        ((__hip_bfloat16*)A)[i] = __float2bfloat16(0.f);

    // biases are step-invariant: hoist. slot s = g*2 + tt  (g: 0=i,1=j,2=f,3=o)
    float bslot[8];
#pragma unroll
    for (int s = 0; s < 8; ++s) {
        const int g = s >> 1, tt = s & 1;
        bslot[s] = bias[g * 256 + wv * 32 + tt * 16 + l15];
    }

    // cell + hidden state: per lane<16, index tt*4 + r -> (batch row r, unit wv*32+tt*16+l15)
    float c[8], hreg[8];
#pragma unroll
    for (int i = 0; i < 8; ++i) { c[i] = 0.f; hreg[i] = 0.f; }

    const int xrow = tid >> 7;          // 0..3
    const int xk2  = (tid & 127) * 2;   // even k within x part

#pragma unroll 1
    for (int t = 0; t < Tn; ++t) {
        __syncthreads();   // barrier 1: everyone done reading A from previous step

        // stage x(t) rows 0..3 (f32 -> bf16)
        {
            const float2 v = *(const float2*)(X + ((size_t)(b0 + xrow) * Tn + t) * In + xk2);
            A[xrow][xk2]     = __float2bfloat16(v.x);
            A[xrow][xk2 + 1] = __float2bfloat16(v.y);
        }
        // stage h(t) (computed in regs at end of previous step; zeros at t=0)
        if (lane < 16) {
#pragma unroll
            for (int tt = 0; tt < 2; ++tt)
#pragma unroll
                for (int r = 0; r < 4; ++r)
                    A[r][In + wv * 32 + tt * 16 + l15] = __float2bfloat16(hreg[tt * 4 + r]);
        }
        __syncthreads();   // barrier 2: A tile ready

        f32x4 acc[8] = {};
#pragma unroll
        for (int kb = 0; kb < 16; ++kb) {
            const bf16x8 a = *(const bf16x8*)&A[l15][kb * 32 + lk * 8];
#pragma unroll
            for (int s = 0; s < 8; ++s) {
                const int g  = s >> 1, tt = s & 1;
                const int nt = g * 16 + wv * 2 + tt;
                const bf16x8 bf = *(const bf16x8*)&Wp[(((size_t)nt * 16 + kb) * 64 + lane) * 8];
                acc[s] = __builtin_amdgcn_mfma_f32_16x16x32_bf16(a, bf, acc[s], 0, 0, 0);
            }
        }

        // gate math (fp32). D layout: col = lane&15, row = (lane>>4)*4 + reg.
        // Real batch rows 0..3 live in lanes 0..15 (regs r=0..3). Other lanes compute pad garbage.
#pragma unroll
        for (int tt = 0; tt < 2; ++tt) {
#pragma unroll
            for (int r = 0; r < 4; ++r) {
                const float pi = acc[0 + tt][r] + bslot[0 + tt];
                const float pj = acc[2 + tt][r] + bslot[2 + tt];
                const float pf = acc[4 + tt][r] + bslot[4 + tt];
                const float po = acc[6 + tt][r] + bslot[6 + tt];
                const float ai = sigmoidf_(pi);
                const float aj = tanhf_(pj);
                const float af = sigmoidf_(pf);
                const float ao = sigmoidf_(po);
                const float cn = ai * aj + c[tt * 4 + r] * af;
                c[tt * 4 + r]  = cn;
                const float hn = ao * tanhf_(cn);
                hreg[tt * 4 + r] = hn;
                if (t == Tn - 1 && lane < 16)
                    out[(size_t)(b0 + r) * Hn + wv * 32 + tt * 16 + l15] = hn;
            }
        }
    }
}

} // namespace

extern "C" void kernel_launch(void* const* d_in, const int* in_sizes, int n_in,
                              void* d_out, int out_size, void* d_ws, size_t ws_size,
                              hipStream_t stream) {
    const float* X    = (const float*)d_in[0];   // [256][512][256] f32
    const float* W    = (const float*)d_in[1];   // [1024][512] f32
    const float* bias = (const float*)d_in[2];   // [1024] f32

    __hip_bfloat16* Wp = (__hip_bfloat16*)d_ws;  // 1 MB packed weights

    pack_w<<<dim3(2048), dim3(256), 0, stream>>>(W, Wp);
    lstm_fused<<<dim3(NWn), dim3(NTHR), 0, stream>>>(X, bias, Wp, (float*)d_out);
}

// Round 3
// 11259.078 us; speedup vs baseline: 1.2732x; 1.2732x over previous
//
#include <hip/hip_runtime.h>
#include <hip/hip_bf16.h>

namespace {

constexpr int Tn   = 512;   // timesteps
constexpr int In   = 256;   // input dim
constexpr int Hn   = 256;   // hidden dim
constexpr int Kn   = 512;   // I + H
constexpr int BB   = 16;    // batch rows per workgroup (full MFMA M-tile, no padding)
constexpr int NW   = 16;    // workgroups (256 / BB)
constexpr int NTHR = 1024;  // 16 waves per workgroup -> 4 waves/SIMD on one CU
constexpr int LDA  = Kn + 8; // LDS row stride (bf16) to break bank conflicts

typedef __attribute__((ext_vector_type(8))) short bf16x8;
typedef __attribute__((ext_vector_type(4))) float f32x4;

// Pack W [1024][512] f32 -> Wp bf16 in exact MFMA-B-fragment order:
// Wp[nt][kb][lane][e], nt = N-tile (16 gate rows), kb = K-block (32), lane 0..63, e 0..7.
// B[k][n] = W[n][k]; lane holds col n = nt*16 + (lane&15), k = kb*32 + (lane>>4)*8 + e.
__global__ void pack_w(const float* __restrict__ W, __hip_bfloat16* __restrict__ Wp) {
    int idx = blockIdx.x * 256 + threadIdx.x;      // 0 .. 524287
    int e   = idx & 7;
    int l   = (idx >> 3) & 63;
    int kb  = (idx >> 9) & 15;
    int nt  = idx >> 13;                           // 0..63
    int n   = nt * 16 + (l & 15);
    int k   = kb * 32 + (l >> 4) * 8 + e;
    Wp[idx] = __float2bfloat16(W[n * Kn + k]);
}

__device__ __forceinline__ float sigmoidf_(float x) { return 1.f / (1.f + __expf(-x)); }
__device__ __forceinline__ float tanhf_(float x)    { return 2.f / (1.f + __expf(-2.f * x)) - 1.f; }

// Persistent LSTM: each workgroup owns 16 batch rows for all 512 steps.
// A-tile [16][512] bf16 in LDS: all rows real ([x_t | h_t]).
// 16 waves; wave w owns hidden units [w*16, w*16+16): per gate g, N-tile g*16 + w.
__global__ __launch_bounds__(NTHR, 4) void lstm_fused(
    const float* __restrict__ X, const float* __restrict__ bias,
    const __hip_bfloat16* __restrict__ Wp, float* __restrict__ out)
{
    __shared__ __hip_bfloat16 A[BB][LDA];

    const int tid  = threadIdx.x;
    const int wv   = tid >> 6;     // wave 0..15
    const int lane = tid & 63;
    const int l15  = lane & 15;
    const int lk   = lane >> 4;    // k-chunk / D-row-quad 0..3
    const int b0   = blockIdx.x * BB;

    // step-invariant per-wave weight base pointers (frag elems: nt*8192 + kb*512 + lane*8)
    const __hip_bfloat16* wp[4];
#pragma unroll
    for (int g = 0; g < 4; ++g)
        wp[g] = Wp + (size_t)(g * 16 + wv) * (16 * 512) + lane * 8;

    // bias: gate g, unit wv*16 + l15 (same for all 4 batch rows this lane holds)
    float bslot[4];
#pragma unroll
    for (int g = 0; g < 4; ++g)
        bslot[g] = bias[g * 256 + wv * 16 + l15];

    // state: lane holds rows lk*4+r (r=0..3) of unit (wv*16 + l15)
    float c[4], h[4];
#pragma unroll
    for (int r = 0; r < 4; ++r) { c[r] = 0.f; h[r] = 0.f; }

    const float* xptr = X + ((size_t)(b0 + wv) * Tn) * In + lane * 4;

#pragma unroll 1
    for (int t = 0; t < Tn; ++t) {
        __syncthreads();   // barrier 1: everyone done reading A from previous step

        // stage x(t): thread loads float4 of row wv, cols lane*4..+3
        {
            const float4 v = *(const float4*)(xptr + (size_t)t * In);
            __hip_bfloat16 tmp[4];
            tmp[0] = __float2bfloat16(v.x);
            tmp[1] = __float2bfloat16(v.y);
            tmp[2] = __float2bfloat16(v.z);
            tmp[3] = __float2bfloat16(v.w);
            *(ushort4*)&A[wv][lane * 4] = *(const ushort4*)tmp;
        }
        // stage h(t): lane writes its 4 state values (zeros at t=0)
#pragma unroll
        for (int r = 0; r < 4; ++r)
            A[lk * 4 + r][In + wv * 16 + l15] = __float2bfloat16(h[r]);

        __syncthreads();   // barrier 2: A tile ready

        // accumulators pre-loaded with bias
        f32x4 acc[4];
#pragma unroll
        for (int g = 0; g < 4; ++g)
            acc[g] = f32x4{bslot[g], bslot[g], bslot[g], bslot[g]};

        // software-pipelined kb loop: register double-buffer on B-fragments
        bf16x8 wbuf[2][4];
#pragma unroll
        for (int g = 0; g < 4; ++g)
            wbuf[0][g] = *(const bf16x8*)(wp[g]);

#pragma unroll
        for (int kb = 0; kb < 16; ++kb) {
            const int cur = kb & 1;
            if (kb < 15) {
#pragma unroll
                for (int g = 0; g < 4; ++g)
                    wbuf[cur ^ 1][g] = *(const bf16x8*)(wp[g] + (kb + 1) * 512);
            }
            const bf16x8 a = *(const bf16x8*)&A[l15][kb * 32 + lk * 8];
#pragma unroll
            for (int g = 0; g < 4; ++g)
                acc[g] = __builtin_amdgcn_mfma_f32_16x16x32_bf16(a, wbuf[cur][g], acc[g], 0, 0, 0);
        }

        // gate math (fp32). D layout: col = lane&15 (unit), row = (lane>>4)*4 + reg (batch row).
#pragma unroll
        for (int r = 0; r < 4; ++r) {
            const float ai = sigmoidf_(acc[0][r]);
            const float aj = tanhf_(acc[1][r]);
            const float af = sigmoidf_(acc[2][r]);
            const float ao = sigmoidf_(acc[3][r]);
            const float cn = ai * aj + c[r] * af;
            c[r] = cn;
            h[r] = ao * tanhf_(cn);
            if (t == Tn - 1)
                out[(size_t)(b0 + lk * 4 + r) * Hn + wv * 16 + l15] = h[r];
        }
    }
}

} // namespace

extern "C" void kernel_launch(void* const* d_in, const int* in_sizes, int n_in,
                              void* d_out, int out_size, void* d_ws, size_t ws_size,
                              hipStream_t stream) {
    const float* X    = (const float*)d_in[0];   // [256][512][256] f32
    const float* W    = (const float*)d_in[1];   // [1024][512] f32
    const float* bias = (const float*)d_in[2];   // [1024] f32

    __hip_bfloat16* Wp = (__hip_bfloat16*)d_ws;  // 1 MB packed weights

    pack_w<<<dim3(2048), dim3(256), 0, stream>>>(W, Wp);
    lstm_fused<<<dim3(NW), dim3(NTHR), 0, stream>>>(X, bias, Wp, (float*)d_out);
}

// Round 4
// 3781.109 us; speedup vs baseline: 3.7913x; 2.9777x over previous
//
#include <hip/hip_runtime.h>
#include <hip/hip_bf16.h>
#include <stdint.h>

namespace {

constexpr int Tn = 512, In = 256, Hn = 256, Kn = 512;

typedef __attribute__((ext_vector_type(8))) short bf16x8;
typedef __attribute__((ext_vector_type(4))) float f32x4;

__device__ __forceinline__ float sigmoidf_(float x) { return 1.f / (1.f + __expf(-x)); }
__device__ __forceinline__ float tanhf_(float x)    { return 2.f / (1.f + __expf(-2.f * x)) - 1.f; }

// ============================ FAST PATH =====================================
// 64 WGs: wg = cl + 16*j. Cluster cl owns batch [16cl,+16); member j owns units [64j,+64).
// 8 waves/WG: w8 = ks*4 + wu. wu -> unit sub-slice [16wu,+16) within j's 64; ks -> K-half.
// Weights resident in VGPRs (128/lane). A-tile [16][512] bf16 staged in LDS, MFMA-frag-linear:
//   frag chunk c = (kb*64 + lane), elem e: holds A[m=lane&15][k=kb*32+(lane>>4)*8+e].

// Pack W [1024][512] f32 -> frag order Wpf[nt2][kb][lane][8], nt2=(j*4+wu)*4+g.
__global__ void pack_w_frag(const float* __restrict__ W, __hip_bfloat16* __restrict__ Wpf) {
    int idx  = blockIdx.x * 256 + threadIdx.x;   // chunk id, 65536 total
    int lane = idx & 63;
    int kb   = (idx >> 6) & 15;
    int nt2  = idx >> 10;                        // 0..63
    int g  = nt2 & 3, wu = (nt2 >> 2) & 3, jj = nt2 >> 4;
    int row = g * 256 + jj * 64 + wu * 16 + (lane & 15);
    int k0  = kb * 32 + (lane >> 4) * 8;
    const float* src = W + (size_t)row * Kn + k0;
    union { __hip_bfloat16 h[8]; bf16x8 v; } u;
#pragma unroll
    for (int e = 0; e < 8; ++e) u.h[e] = __float2bfloat16(src[e]);
    *(bf16x8*)(Wpf + (size_t)idx * 8) = u.v;
}

__global__ __launch_bounds__(512, 2) void lstm_cluster(
    const float* __restrict__ X, const float* __restrict__ bias,
    const __hip_bfloat16* __restrict__ Wpf, __hip_bfloat16* __restrict__ hbuf,
    uint32_t* cnt, float* __restrict__ out)
{
    __shared__ __hip_bfloat16 Afr[8192];   // 16 KB frag-linear A (x: bytes [0,8K), h: [8K,16K))
    __shared__ f32x4 Red[4][4][64];        // 16 KB K-split partial sums

    const int tid = threadIdx.x, lane = tid & 63, w8 = tid >> 6;
    const int wu = w8 & 3, ks = w8 >> 2;
    const int l15 = lane & 15, lk = lane >> 4;
    const int wg = blockIdx.x, cl = wg & 15, j = wg >> 4;

    // ---- resident weights: 32 frags = 128 VGPRs ----
    bf16x8 wf[4][8];
#pragma unroll
    for (int g = 0; g < 4; ++g)
#pragma unroll
        for (int i = 0; i < 8; ++i) {
            const int nt2 = (j * 4 + wu) * 4 + g, kb = ks * 8 + i;
            wf[g][i] = *(const bf16x8*)(Wpf + ((size_t)(nt2 * 16 + kb) * 64 + lane) * 8);
        }

    float bg[4];
#pragma unroll
    for (int g = 0; g < 4; ++g) bg[g] = bias[g * 256 + j * 64 + wu * 16 + l15];

    float c4[4] = {0.f, 0.f, 0.f, 0.f};
    uint32_t* mycnt = cnt + wg * 32;

#pragma unroll 1
    for (int t = 0; t < Tn; ++t) {
        // ---- stage x: waves ks==0 (issue loads early, spin overlaps latency) ----
        float4 xv[2][2];
        if (ks == 0) {
            const int b = wu * 4 + lk;
#pragma unroll
            for (int cc = 0; cc < 2; ++cc) {
                const float* xs = X + ((size_t)(cl * 16 + b) * Tn + t) * In + (l15 + cc * 16) * 8;
                xv[cc][0] = *(const float4*)xs;
                xv[cc][1] = *(const float4*)(xs + 4);
            }
        }
        // ---- spin: wave 0, lanes 0..3 poll cluster mates (agent-scope, L2-coherent) ----
        if (w8 == 0 && lane < 4 && lane != j && t > 0) {
            const uint32_t* mc = cnt + (cl + 16 * lane) * 32;
            int guard = 0;
            while (__hip_atomic_load(mc, __ATOMIC_RELAXED, __HIP_MEMORY_SCOPE_AGENT) < (uint32_t)t
                   && ++guard < (1 << 22))
                __builtin_amdgcn_s_sleep(2);
        }
        if (ks == 0) {
            const int b = wu * 4 + lk;
#pragma unroll
            for (int cc = 0; cc < 2; ++cc) {
                const int o8 = l15 + cc * 16;
                union { __hip_bfloat16 h[8]; bf16x8 v; } u;
                u.h[0] = __float2bfloat16(xv[cc][0].x); u.h[1] = __float2bfloat16(xv[cc][0].y);
                u.h[2] = __float2bfloat16(xv[cc][0].z); u.h[3] = __float2bfloat16(xv[cc][0].w);
                u.h[4] = __float2bfloat16(xv[cc][1].x); u.h[5] = __float2bfloat16(xv[cc][1].y);
                u.h[6] = __float2bfloat16(xv[cc][1].z); u.h[7] = __float2bfloat16(xv[cc][1].w);
                *(bf16x8*)&Afr[(b + 16 * o8) * 8] = u.v;
            }
        }
        __syncthreads();   // B1: gate passed (h(t) globally visible), x staged

        // ---- stage h: waves ks==1, 16-B coalesced from frag-layout hbuf ----
        if (ks == 1) {
            if (t > 0) {
                __threadfence();   // acquire: invalidate stale L2 before reading mates' h
                const char* src = (const char*)hbuf + (size_t)((t & 1) * 16 + cl) * 8192;
                char* dst = (char*)Afr + 8192;
#pragma unroll
                for (int cc = 0; cc < 2; ++cc) {
                    const int off = wu * 2048 + cc * 1024 + lane * 16;
                    *(bf16x8*)(dst + off) = *(const bf16x8*)(src + off);
                }
            } else {
                char* dst = (char*)Afr + 8192;
                const bf16x8 z = {};
#pragma unroll
                for (int cc = 0; cc < 2; ++cc) {
                    const int off = wu * 2048 + cc * 1024 + lane * 16;
                    *(bf16x8*)(dst + off) = z;
                }
            }
        }
        __syncthreads();   // B2: A tile ready

        // ---- MFMA: 8 frags x 4 gates on resident weights ----
        f32x4 acc[4] = {};
        bf16x8 af[8];
#pragma unroll
        for (int i = 0; i < 8; ++i)
            af[i] = *(const bf16x8*)&Afr[((ks * 8 + i) * 64 + lane) * 8];
#pragma unroll
        for (int i = 0; i < 8; ++i)
#pragma unroll
            for (int g = 0; g < 4; ++g)
                acc[g] = __builtin_amdgcn_mfma_f32_16x16x32_bf16(af[i], wf[g][i], acc[g], 0, 0, 0);

        if (ks == 1) {
#pragma unroll
            for (int g = 0; g < 4; ++g) Red[wu][g][lane] = acc[g];
        }
        __syncthreads();   // B3: partials ready

        // ---- reduce + gate math (ks==0 waves) ----
        if (ks == 0) {
#pragma unroll
            for (int g = 0; g < 4; ++g) acc[g] += Red[wu][g][lane];
            char* hb = (char*)hbuf + (size_t)(((t + 1) & 1) * 16 + cl) * 8192;
#pragma unroll
            for (int r = 0; r < 4; ++r) {
                const float pi = acc[0][r] + bg[0];
                const float pj = acc[1][r] + bg[1];
                const float pf = acc[2][r] + bg[2];
                const float po = acc[3][r] + bg[3];
                const float ai = sigmoidf_(pi);
                const float aj = tanhf_(pj);
                const float afv = sigmoidf_(pf);
                const float ao = sigmoidf_(po);
                const float cn = ai * aj + c4[r] * afv;
                c4[r] = cn;
                const float hn = ao * tanhf_(cn);
                if (t < Tn - 1) {
                    // frag-layout position: chunk = b + 16*(u_global>>3), e = u_global&7
                    const int off = 16 * ((lk * 4 + r) + 16 * (8 * j + 2 * wu + (l15 >> 3)))
                                  + 2 * (l15 & 7);
                    *(__hip_bfloat16*)(hb + off) = __float2bfloat16(hn);
                } else {
                    out[(size_t)(cl * 16 + lk * 4 + r) * Hn + j * 64 + wu * 16 + l15] = hn;
                }
            }
        }
        __syncthreads();   // B4: h stores drained (barrier implies vmcnt(0))
        if (tid == 0)
            __hip_atomic_fetch_add(mycnt, 1u, __ATOMIC_RELEASE, __HIP_MEMORY_SCOPE_AGENT);
    }
}

// ====================== FALLBACK (R3, passing, 11.3 ms) =====================
__global__ void pack_w(const float* __restrict__ W, __hip_bfloat16* __restrict__ Wp) {
    int idx = blockIdx.x * 256 + threadIdx.x;
    int e = idx & 7, l = (idx >> 3) & 63, kb = (idx >> 9) & 15, nt = idx >> 13;
    int n = nt * 16 + (l & 15);
    int k = kb * 32 + (l >> 4) * 8 + e;
    Wp[idx] = __float2bfloat16(W[n * Kn + k]);
}

__global__ __launch_bounds__(1024, 4) void lstm_fused(
    const float* __restrict__ X, const float* __restrict__ bias,
    const __hip_bfloat16* __restrict__ Wp, float* __restrict__ out)
{
    constexpr int LDA = Kn + 8;
    __shared__ __hip_bfloat16 A[16][LDA];
    const int tid = threadIdx.x, wv = tid >> 6, lane = tid & 63;
    const int l15 = lane & 15, lk = lane >> 4, b0 = blockIdx.x * 16;
    const __hip_bfloat16* wp[4];
#pragma unroll
    for (int g = 0; g < 4; ++g) wp[g] = Wp + (size_t)(g * 16 + wv) * (16 * 512) + lane * 8;
    float bslot[4];
#pragma unroll
    for (int g = 0; g < 4; ++g) bslot[g] = bias[g * 256 + wv * 16 + l15];
    float c[4], h[4];
#pragma unroll
    for (int r = 0; r < 4; ++r) { c[r] = 0.f; h[r] = 0.f; }
    const float* xptr = X + ((size_t)(b0 + wv) * Tn) * In + lane * 4;
#pragma unroll 1
    for (int t = 0; t < Tn; ++t) {
        __syncthreads();
        {
            const float4 v = *(const float4*)(xptr + (size_t)t * In);
            __hip_bfloat16 tmp[4];
            tmp[0] = __float2bfloat16(v.x); tmp[1] = __float2bfloat16(v.y);
            tmp[2] = __float2bfloat16(v.z); tmp[3] = __float2bfloat16(v.w);
            *(ushort4*)&A[wv][lane * 4] = *(const ushort4*)tmp;
        }
#pragma unroll
        for (int r = 0; r < 4; ++r)
            A[lk * 4 + r][In + wv * 16 + l15] = __float2bfloat16(h[r]);
        __syncthreads();
        f32x4 acc[4];
#pragma unroll
        for (int g = 0; g < 4; ++g) acc[g] = f32x4{bslot[g], bslot[g], bslot[g], bslot[g]};
        bf16x8 wbuf[2][4];
#pragma unroll
        for (int g = 0; g < 4; ++g) wbuf[0][g] = *(const bf16x8*)(wp[g]);
#pragma unroll
        for (int kb = 0; kb < 16; ++kb) {
            const int cur = kb & 1;
            if (kb < 15) {
#pragma unroll
                for (int g = 0; g < 4; ++g)
                    wbuf[cur ^ 1][g] = *(const bf16x8*)(wp[g] + (kb + 1) * 512);
            }
            const bf16x8 a = *(const bf16x8*)&A[l15][kb * 32 + lk * 8];
#pragma unroll
            for (int g = 0; g < 4; ++g)
                acc[g] = __builtin_amdgcn_mfma_f32_16x16x32_bf16(a, wbuf[cur][g], acc[g], 0, 0, 0);
        }
#pragma unroll
        for (int r = 0; r < 4; ++r) {
            const float ai = sigmoidf_(acc[0][r]);
            const float aj = tanhf_(acc[1][r]);
            const float af = sigmoidf_(acc[2][r]);
            const float ao = sigmoidf_(acc[3][r]);
            const float cn = ai * aj + c[r] * af;
            c[r] = cn;
            h[r] = ao * tanhf_(cn);
            if (t == Tn - 1)
                out[(size_t)(b0 + lk * 4 + r) * Hn + wv * 16 + l15] = h[r];
        }
    }
}

} // namespace

extern "C" void kernel_launch(void* const* d_in, const int* in_sizes, int n_in,
                              void* d_out, int out_size, void* d_ws, size_t ws_size,
                              hipStream_t stream) {
    const float* X    = (const float*)d_in[0];   // [256][512][256] f32
    const float* W    = (const float*)d_in[1];   // [1024][512] f32
    const float* bias = (const float*)d_in[2];   // [1024] f32

    if (ws_size >= (size_t)0x142000) {
        // fast path: Wpf @0 (1 MB), hbuf @1 MB (256 KB), counters @1.25 MB (8 KB)
        __hip_bfloat16* Wpf  = (__hip_bfloat16*)d_ws;
        __hip_bfloat16* hbuf = (__hip_bfloat16*)((char*)d_ws + 0x100000);
        uint32_t*       cnt  = (uint32_t*)((char*)d_ws + 0x140000);
        hipMemsetAsync((void*)cnt, 0, 8192, stream);
        pack_w_frag<<<dim3(256), dim3(256), 0, stream>>>(W, Wpf);
        lstm_cluster<<<dim3(64), dim3(512), 0, stream>>>(X, bias, Wpf, hbuf, cnt, (float*)d_out);
    } else {
        __hip_bfloat16* Wp = (__hip_bfloat16*)d_ws;  // 1 MB packed weights
        pack_w<<<dim3(2048), dim3(256), 0, stream>>>(W, Wp);
        lstm_fused<<<dim3(16), dim3(1024), 0, stream>>>(X, bias, Wp, (float*)d_out);
    }
}

// Round 5
// 1705.727 us; speedup vs baseline: 8.4042x; 2.2167x over previous
//
#include <hip/hip_runtime.h>
#include <hip/hip_bf16.h>
#include <stdint.h>

namespace {

constexpr int Tn = 512, In = 256, Hn = 256, Kn = 512;

typedef __attribute__((ext_vector_type(8))) short bf16x8;
typedef __attribute__((ext_vector_type(4))) float f32x4;

__device__ __forceinline__ float sigmoidf_(float x) { return 1.f / (1.f + __expf(-x)); }
__device__ __forceinline__ float tanhf_(float x)    { return 2.f / (1.f + __expf(-2.f * x)) - 1.f; }

// LLC-direct (agent-coherent) 16B access: sc1 bypasses/stays coherent past the
// per-XCD L2, so cross-XCD handoff needs NO wbl2/inv cache maintenance.
__device__ __forceinline__ void store16_llc(void* p, bf16x8 v) {
    asm volatile("global_store_dwordx4 %0, %1, off sc1" :: "v"(p), "v"(v) : "memory");
}
__device__ __forceinline__ bf16x8 load16_llc(const void* p) {
    bf16x8 r;
    asm volatile("global_load_dwordx4 %0, %1, off sc1" : "=v"(r) : "v"(p) : "memory");
    return r;
}

// involutive chunk swizzle for the A-fragment LDS tile: kills the 16-way
// ds_write_b128 conflict in x-staging; reads apply the same map (bijective
// within each 16-chunk group, so read conflict-freedom is preserved)
__device__ __forceinline__ int swz(int c) { return c ^ ((c >> 4) & 15); }

// ============================ FAST PATH =====================================
// 64 WGs: wg = cl + 16*j. Cluster cl owns batch [16cl,+16); member j owns units [64j,+64).
// 8 waves/WG: w8 = ks*4 + wu. wu -> unit sub-slice [16wu,+16); ks -> K-half.
// Weights resident in VGPR/AGPR. A-tile staged in LDS in MFMA-frag-linear chunks:
//   chunk c = kb*64 + lane, elem e holds A[m=lane&15][k = kb*32 + (lane>>4)*8 + e].

__global__ void pack_w_frag(const float* __restrict__ W, __hip_bfloat16* __restrict__ Wpf,
                            uint32_t* __restrict__ flags) {
    int idx  = blockIdx.x * 256 + threadIdx.x;   // chunk id, 65536 total
    int lane = idx & 63;
    int kb   = (idx >> 6) & 15;
    int nt2  = idx >> 10;                        // 0..63
    int g  = nt2 & 3, wu = (nt2 >> 2) & 3, jj = nt2 >> 4;
    int row = g * 256 + jj * 64 + wu * 16 + (lane & 15);
    int k0  = kb * 32 + (lane >> 4) * 8;
    const float* src = W + (size_t)row * Kn + k0;
    union { __hip_bfloat16 h[8]; bf16x8 v; } u;
#pragma unroll
    for (int e = 0; e < 8; ++e) u.h[e] = __float2bfloat16(src[e]);
    *(bf16x8*)(Wpf + (size_t)idx * 8) = u.v;
    // zero the 64 member-flags at LLC scope (kernel boundary orders this
    // before lstm_cluster's polls; sc1 avoids stale-LLC vs-L2 hazards)
    if (blockIdx.x == 0 && threadIdx.x < 64)
        __hip_atomic_store(flags + threadIdx.x * 16, 0u,
                           __ATOMIC_RELAXED, __HIP_MEMORY_SCOPE_AGENT);
}

__global__ __launch_bounds__(512, 2) void lstm_cluster(
    const float* __restrict__ X, const float* __restrict__ bias,
    const __hip_bfloat16* __restrict__ Wpf, __hip_bfloat16* __restrict__ hbuf,
    uint32_t* __restrict__ flags, float* __restrict__ out)
{
    __shared__ bf16x8 AfrV[1024];          // 16 KB frag-linear A (x: chunks 0..511, h: 512..1023)
    __shared__ f32x4 Red[4][4][64];        // 16 KB K-split partial sums
    __shared__ __hip_bfloat16 Hc[16][72];  // compact h tile [batch][unit], padded

    const int tid = threadIdx.x, lane = tid & 63, w8 = tid >> 6;
    const int wu = w8 & 3, ks = w8 >> 2;
    const int l15 = lane & 15, lk = lane >> 4;
    const int wg = blockIdx.x, cl = wg & 15, j = wg >> 4;

    // ---- resident weights: 32 frags / lane ----
    bf16x8 wf[4][8];
#pragma unroll
    for (int g = 0; g < 4; ++g)
#pragma unroll
        for (int i = 0; i < 8; ++i) {
            const int nt2 = (j * 4 + wu) * 4 + g, kb = ks * 8 + i;
            wf[g][i] = *(const bf16x8*)(Wpf + ((size_t)(nt2 * 16 + kb) * 64 + lane) * 8);
        }

    float bg[4];
#pragma unroll
    for (int g = 0; g < 4; ++g) bg[g] = bias[g * 256 + j * 64 + wu * 16 + l15];

    float c4[4] = {0.f, 0.f, 0.f, 0.f};
    uint32_t* myflag = flags + (cl * 4 + j) * 16;

    // zero whole A tile (h region must be zero for t=0)
    {
        const bf16x8 z = {};
        AfrV[tid] = z; AfrV[tid + 512] = z;
    }
    __syncthreads();

#pragma unroll 1
    for (int t = 0; t < Tn; ++t) {
        // ---- export h(t) (computed last step, sitting in Hc) to LLC + flag ----
        if (w8 == 0 && t > 0) {
            const int o = lane >> 4, r = lane & 15;
            char* HB = (char*)hbuf + (size_t)(((t & 1) * 16 + cl) * 8192) + j * 2048;
#pragma unroll
            for (int ii = 0; ii < 2; ++ii) {
                const int oo = o + 4 * ii;
                const bf16x8 e = *(const bf16x8*)&Hc[r][oo * 8];
                store16_llc(HB + (oo >> 2) * 1024 + (oo & 3) * 256 + r * 16, e);
            }
            asm volatile("s_waitcnt vmcnt(0)" ::: "memory");   // data at LLC before flag
            if (lane == 0)
                __hip_atomic_store(myflag, (uint32_t)t,
                                   __ATOMIC_RELAXED, __HIP_MEMORY_SCOPE_AGENT);
        }

        // ---- stage x(t): ks==0 waves (frag-linear, swizzled) ----
        if (ks == 0) {
            const int b = wu * 4 + lk;
            const float* xs = X + ((size_t)(cl * 16 + b) * Tn + t) * In;
#pragma unroll
            for (int cc = 0; cc < 2; ++cc) {
                const int o8 = l15 + cc * 16;
                const float4 v0 = *(const float4*)(xs + o8 * 8);
                const float4 v1 = *(const float4*)(xs + o8 * 8 + 4);
                union { __hip_bfloat16 h[8]; bf16x8 v; } u;
                u.h[0] = __float2bfloat16(v0.x); u.h[1] = __float2bfloat16(v0.y);
                u.h[2] = __float2bfloat16(v0.z); u.h[3] = __float2bfloat16(v0.w);
                u.h[4] = __float2bfloat16(v1.x); u.h[5] = __float2bfloat16(v1.y);
                u.h[6] = __float2bfloat16(v1.z); u.h[7] = __float2bfloat16(v1.w);
                AfrV[swz(b + 16 * o8)] = u.v;
            }
        }

        // ---- import h(t): ks==1 waves; wave wu polls member wu then copies 2 KB ----
        if (ks == 1 && t > 0) {
            const uint32_t* mf = flags + (cl * 4 + wu) * 16;
            uint32_t f; int guard = 0;
            do {
                f = __hip_atomic_load(mf, __ATOMIC_RELAXED, __HIP_MEMORY_SCOPE_AGENT);
            } while (f < (uint32_t)t && ++guard < (1 << 20));
            const char* src = (const char*)hbuf + (size_t)(((t & 1) * 16 + cl) * 8192) + wu * 2048;
            const bf16x8 r0 = load16_llc(src + lane * 16);
            const bf16x8 r1 = load16_llc(src + lane * 16 + 1024);
            asm volatile("s_waitcnt vmcnt(0)" ::: "memory");
            __builtin_amdgcn_sched_barrier(0);
            AfrV[swz(512 + wu * 128 + lane)]      = r0;
            AfrV[swz(512 + wu * 128 + lane + 64)] = r1;
        }
        __syncthreads();   // B2: A tile ready

        // ---- MFMA: 8 frags x 4 gates on resident weights ----
        f32x4 acc[4] = {};
        bf16x8 af[8];
#pragma unroll
        for (int i = 0; i < 8; ++i)
            af[i] = AfrV[swz((ks * 8 + i) * 64 + lane)];
#pragma unroll
        for (int i = 0; i < 8; ++i)
#pragma unroll
            for (int g = 0; g < 4; ++g)
                acc[g] = __builtin_amdgcn_mfma_f32_16x16x32_bf16(af[i], wf[g][i], acc[g], 0, 0, 0);

        if (ks == 1) {
#pragma unroll
            for (int g = 0; g < 4; ++g) Red[wu][g][lane] = acc[g];
        }
        __syncthreads();   // B3: partials ready

        // ---- reduce + gate math (ks==0 waves); h -> compact LDS tile ----
        if (ks == 0) {
#pragma unroll
            for (int g = 0; g < 4; ++g) acc[g] += Red[wu][g][lane];
#pragma unroll
            for (int r = 0; r < 4; ++r) {
                const float pi = acc[0][r] + bg[0];
                const float pj = acc[1][r] + bg[1];
                const float pf = acc[2][r] + bg[2];
                const float po = acc[3][r] + bg[3];
                const float ai = sigmoidf_(pi);
                const float aj = tanhf_(pj);
                const float afv = sigmoidf_(pf);
                const float ao = sigmoidf_(po);
                const float cn = ai * aj + c4[r] * afv;
                c4[r] = cn;
                const float hn = ao * tanhf_(cn);
                if (t < Tn - 1)
                    Hc[lk * 4 + r][wu * 16 + l15] = __float2bfloat16(hn);
                else
                    out[(size_t)(cl * 16 + lk * 4 + r) * Hn + j * 64 + wu * 16 + l15] = hn;
            }
        }
        __syncthreads();   // B4: Hc complete (export reads it next iteration)
    }
}

// ====================== FALLBACK (R3, passing) ==============================
__global__ void pack_w(const float* __restrict__ W, __hip_bfloat16* __restrict__ Wp) {
    int idx = blockIdx.x * 256 + threadIdx.x;
    int e = idx & 7, l = (idx >> 3) & 63, kb = (idx >> 9) & 15, nt = idx >> 13;
    int n = nt * 16 + (l & 15);
    int k = kb * 32 + (l >> 4) * 8 + e;
    Wp[idx] = __float2bfloat16(W[n * Kn + k]);
}

__global__ __launch_bounds__(1024, 4) void lstm_fused(
    const float* __restrict__ X, const float* __restrict__ bias,
    const __hip_bfloat16* __restrict__ Wp, float* __restrict__ out)
{
    constexpr int LDA = Kn + 8;
    __shared__ __hip_bfloat16 A[16][LDA];
    const int tid = threadIdx.x, wv = tid >> 6, lane = tid & 63;
    const int l15 = lane & 15, lk = lane >> 4, b0 = blockIdx.x * 16;
    const __hip_bfloat16* wp[4];
#pragma unroll
    for (int g = 0; g < 4; ++g) wp[g] = Wp + (size_t)(g * 16 + wv) * (16 * 512) + lane * 8;
    float bslot[4];
#pragma unroll
    for (int g = 0; g < 4; ++g) bslot[g] = bias[g * 256 + wv * 16 + l15];
    float c[4], h[4];
#pragma unroll
    for (int r = 0; r < 4; ++r) { c[r] = 0.f; h[r] = 0.f; }
    const float* xptr = X + ((size_t)(b0 + wv) * Tn) * In + lane * 4;
#pragma unroll 1
    for (int t = 0; t < Tn; ++t) {
        __syncthreads();
        {
            const float4 v = *(const float4*)(xptr + (size_t)t * In);
            __hip_bfloat16 tmp[4];
            tmp[0] = __float2bfloat16(v.x); tmp[1] = __float2bfloat16(v.y);
            tmp[2] = __float2bfloat16(v.z); tmp[3] = __float2bfloat16(v.w);
            *(ushort4*)&A[wv][lane * 4] = *(const ushort4*)tmp;
        }
#pragma unroll
        for (int r = 0; r < 4; ++r)
            A[lk * 4 + r][In + wv * 16 + l15] = __float2bfloat16(h[r]);
        __syncthreads();
        f32x4 acc[4];
#pragma unroll
        for (int g = 0; g < 4; ++g) acc[g] = f32x4{bslot[g], bslot[g], bslot[g], bslot[g]};
        bf16x8 wbuf[2][4];
#pragma unroll
        for (int g = 0; g < 4; ++g) wbuf[0][g] = *(const bf16x8*)(wp[g]);
#pragma unroll
        for (int kb = 0; kb < 16; ++kb) {
            const int cur = kb & 1;
            if (kb < 15) {
#pragma unroll
                for (int g = 0; g < 4; ++g)
                    wbuf[cur ^ 1][g] = *(const bf16x8*)(wp[g] + (kb + 1) * 512);
            }
            const bf16x8 a = *(const bf16x8*)&A[l15][kb * 32 + lk * 8];
#pragma unroll
            for (int g = 0; g < 4; ++g)
                acc[g] = __builtin_amdgcn_mfma_f32_16x16x32_bf16(a, wbuf[cur][g], acc[g], 0, 0, 0);
        }
#pragma unroll
        for (int r = 0; r < 4; ++r) {
            const float ai = sigmoidf_(acc[0][r]);
            const float aj = tanhf_(acc[1][r]);
            const float af = sigmoidf_(acc[2][r]);
            const float ao = sigmoidf_(acc[3][r]);
            const float cn = ai * aj + c[r] * af;
            c[r] = cn;
            h[r] = ao * tanhf_(cn);
            if (t == Tn - 1)
                out[(size_t)(b0 + lk * 4 + r) * Hn + wv * 16 + l15] = h[r];
        }
    }
}

} // namespace

extern "C" void kernel_launch(void* const* d_in, const int* in_sizes, int n_in,
                              void* d_out, int out_size, void* d_ws, size_t ws_size,
                              hipStream_t stream) {
    const float* X    = (const float*)d_in[0];   // [256][512][256] f32
    const float* W    = (const float*)d_in[1];   // [1024][512] f32
    const float* bias = (const float*)d_in[2];   // [1024] f32

    if (ws_size >= (size_t)0x142000) {
        // fast path: Wpf @0 (1 MB), hbuf @1 MB (256 KB), flags @1.25 MB (4 KB)
        __hip_bfloat16* Wpf  = (__hip_bfloat16*)d_ws;
        __hip_bfloat16* hbuf = (__hip_bfloat16*)((char*)d_ws + 0x100000);
        uint32_t*       flags = (uint32_t*)((char*)d_ws + 0x140000);
        pack_w_frag<<<dim3(256), dim3(256), 0, stream>>>(W, Wpf, flags);
        lstm_cluster<<<dim3(64), dim3(512), 0, stream>>>(X, bias, Wpf, hbuf, flags, (float*)d_out);
    } else {
        __hip_bfloat16* Wp = (__hip_bfloat16*)d_ws;  // 1 MB packed weights
        pack_w<<<dim3(2048), dim3(256), 0, stream>>>(W, Wp);
        lstm_fused<<<dim3(16), dim3(1024), 0, stream>>>(X, bias, Wp, (float*)d_out);
    }
}